// Round 3
// baseline (590.424 us; speedup 1.0000x reference)
//
#include <hip/hip_runtime.h>

#define D_DIM 160
#define H_DIM 192
#define W_DIM 160
#define NVOX (D_DIM * H_DIM * W_DIM)
#define NB_STEPS 7

struct F3 {
    float x, y, z;
};

// MODE 0: AoS input (raw vec, fuse 1/128 scale) -> SoA output
// MODE 1: SoA -> SoA
// MODE 2: SoA -> AoS output (final step)
template <int MODE>
__global__ __launch_bounds__(256) void warp_step(const float* __restrict__ v,
                                                 float* __restrict__ out) {
    int idx = blockIdx.x * blockDim.x + threadIdx.x;
    if (idx >= NVOX) return;

    int w = idx % W_DIM;
    int t = idx / W_DIM;
    int h = t % H_DIM;
    int d = t / H_DIM;

    const float s = 0.0078125f;  // 1/128

    float flow_d, flow_h, flow_w;
    if (MODE == 0) {
        F3 f = reinterpret_cast<const F3*>(v)[idx];
        flow_d = f.x * s;
        flow_h = f.y * s;
        flow_w = f.z * s;
    } else {
        flow_d = v[idx];
        flow_h = v[NVOX + idx];
        flow_w = v[2 * NVOX + idx];
    }

    float ld = fminf(fmaxf((float)d + flow_d, 0.0f), (float)(D_DIM - 1));
    float lh = fminf(fmaxf((float)h + flow_h, 0.0f), (float)(H_DIM - 1));
    float lw = fminf(fmaxf((float)w + flow_w, 0.0f), (float)(W_DIM - 1));

    float fd = floorf(ld), fh = floorf(lh), fw = floorf(lw);
    int d0 = (int)fd, h0 = (int)fh, w0 = (int)fw;
    int d1 = min(d0 + 1, D_DIM - 1);
    int h1 = min(h0 + 1, H_DIM - 1);
    int w1 = min(w0 + 1, W_DIM - 1);

    float wd = ld - fd, wh = lh - fh, ww = lw - fw;
    float od = 1.0f - wd, oh = 1.0f - wh, ow = 1.0f - ww;

    int r00 = (d0 * H_DIM + h0) * W_DIM;
    int r01 = (d0 * H_DIM + h1) * W_DIM;
    int r10 = (d1 * H_DIM + h0) * W_DIM;
    int r11 = (d1 * H_DIM + h1) * W_DIM;

    float w000 = od * oh * ow;
    float w001 = od * oh * ww;
    float w010 = od * wh * ow;
    float w011 = od * wh * ww;
    float w100 = wd * oh * ow;
    float w101 = wd * oh * ww;
    float w110 = wd * wh * ow;
    float w111 = wd * wh * ww;

    float acc0 = 0.0f, acc1 = 0.0f, acc2 = 0.0f;

    if (MODE == 0) {
        // gather from raw AoS input (unscaled corners; scale folded at the end)
#define CORNER_AOS(ROW, COL, WT)                                      \
        {                                                             \
            F3 c = reinterpret_cast<const F3*>(v)[(ROW) + (COL)];     \
            acc0 = fmaf(WT, c.x, acc0);                               \
            acc1 = fmaf(WT, c.y, acc1);                               \
            acc2 = fmaf(WT, c.z, acc2);                               \
        }
        CORNER_AOS(r00, w0, w000);
        CORNER_AOS(r00, w1, w001);
        CORNER_AOS(r01, w0, w010);
        CORNER_AOS(r01, w1, w011);
        CORNER_AOS(r10, w0, w100);
        CORNER_AOS(r10, w1, w101);
        CORNER_AOS(r11, w0, w110);
        CORNER_AOS(r11, w1, w111);
#undef CORNER_AOS
    } else {
        const float* p0 = v;
        const float* p1 = v + NVOX;
        const float* p2 = v + 2 * NVOX;
#define CORNER_SOA(ROW, COL, WT)                \
        {                                       \
            int pos = (ROW) + (COL);            \
            acc0 = fmaf(WT, p0[pos], acc0);     \
            acc1 = fmaf(WT, p1[pos], acc1);     \
            acc2 = fmaf(WT, p2[pos], acc2);     \
        }
        CORNER_SOA(r00, w0, w000);
        CORNER_SOA(r00, w1, w001);
        CORNER_SOA(r01, w0, w010);
        CORNER_SOA(r01, w1, w011);
        CORNER_SOA(r10, w0, w100);
        CORNER_SOA(r10, w1, w101);
        CORNER_SOA(r11, w0, w110);
        CORNER_SOA(r11, w1, w111);
#undef CORNER_SOA
    }

    if (MODE == 0) {
        // out = s*f + s*acc (flow_* already = s*f)
        out[idx] = flow_d + s * acc0;
        out[NVOX + idx] = flow_h + s * acc1;
        out[2 * NVOX + idx] = flow_w + s * acc2;
    } else if (MODE == 1) {
        out[idx] = flow_d + acc0;
        out[NVOX + idx] = flow_h + acc1;
        out[2 * NVOX + idx] = flow_w + acc2;
    } else {
        F3 o;
        o.x = flow_d + acc0;
        o.y = flow_h + acc1;
        o.z = flow_w + acc2;
        reinterpret_cast<F3*>(out)[idx] = o;
    }
}

extern "C" void kernel_launch(void* const* d_in, const int* in_sizes, int n_in,
                              void* d_out, int out_size, void* d_ws, size_t ws_size,
                              hipStream_t stream) {
    const float* vec = (const float*)d_in[0];
    float* A = (float*)d_ws;   // SoA scratch (59 MB)
    float* O = (float*)d_out;  // used as SoA scratch mid-flight; AoS at the end

    int grid = NVOX / 256;  // 19200, exact

    // X1=O, X2=A, X3=O, X4=A, X5=O, X6=A, X7=d_out (AoS)
    warp_step<0><<<grid, 256, 0, stream>>>(vec, O);  // AoS->SoA, fused scale
    warp_step<1><<<grid, 256, 0, stream>>>(O, A);
    warp_step<1><<<grid, 256, 0, stream>>>(A, O);
    warp_step<1><<<grid, 256, 0, stream>>>(O, A);
    warp_step<1><<<grid, 256, 0, stream>>>(A, O);
    warp_step<1><<<grid, 256, 0, stream>>>(O, A);
    warp_step<2><<<grid, 256, 0, stream>>>(A, O);  // SoA->AoS final
}

// Round 4
// 265.219 us; speedup vs baseline: 2.2262x; 2.2262x over previous
//
#include <hip/hip_runtime.h>

#define D_DIM 160
#define H_DIM 192
#define W_DIM 160
#define NVOX (D_DIM * H_DIM * W_DIM)

typedef _Float16 half_t;
typedef __attribute__((ext_vector_type(4))) _Float16 H4;  // x,y,z,pad : 8 bytes

struct F3 {
    float x, y, z;
};

// vec (fp32 AoS, float4-vectorized) * 1/128 -> fp16 H4 state. 4 voxels/thread.
__global__ __launch_bounds__(256) void scale_to_h(const float4* __restrict__ in,
                                                  H4* __restrict__ out, int n) {
    int i = blockIdx.x * blockDim.x + threadIdx.x;
    if (i >= n) return;
    float4 a = in[3 * i + 0];
    float4 b = in[3 * i + 1];
    float4 c = in[3 * i + 2];
    const float s = 0.0078125f;
    H4 o0 = {(half_t)(a.x * s), (half_t)(a.y * s), (half_t)(a.z * s), (half_t)0.f};
    H4 o1 = {(half_t)(a.w * s), (half_t)(b.x * s), (half_t)(b.y * s), (half_t)0.f};
    H4 o2 = {(half_t)(b.z * s), (half_t)(b.w * s), (half_t)(c.x * s), (half_t)0.f};
    H4 o3 = {(half_t)(c.y * s), (half_t)(c.z * s), (half_t)(c.w * s), (half_t)0.f};
    out[4 * i + 0] = o0;
    out[4 * i + 1] = o1;
    out[4 * i + 2] = o2;
    out[4 * i + 3] = o3;
}

// One scaling-and-squaring step on fp16 state. All math fp32.
// MODE 1: fp16 -> fp16.  MODE 2: fp16 -> fp32 AoS (final step into d_out).
template <int MODE>
__global__ __launch_bounds__(256) void warp_h(const H4* __restrict__ v,
                                              void* __restrict__ outp) {
    int idx = blockIdx.x * blockDim.x + threadIdx.x;
    if (idx >= NVOX) return;

    int w = idx % W_DIM;
    int t = idx / W_DIM;
    int h = t % H_DIM;
    int d = t / H_DIM;

    H4 f = v[idx];
    float flow_d = (float)f.x;
    float flow_h = (float)f.y;
    float flow_w = (float)f.z;

    float ld = fminf(fmaxf((float)d + flow_d, 0.0f), (float)(D_DIM - 1));
    float lh = fminf(fmaxf((float)h + flow_h, 0.0f), (float)(H_DIM - 1));
    float lw = fminf(fmaxf((float)w + flow_w, 0.0f), (float)(W_DIM - 1));

    float fd = floorf(ld), fh = floorf(lh), fw = floorf(lw);
    int d0 = (int)fd, h0 = (int)fh, w0 = (int)fw;
    int d1 = min(d0 + 1, D_DIM - 1);
    int h1 = min(h0 + 1, H_DIM - 1);
    int w1 = min(w0 + 1, W_DIM - 1);

    float wd = ld - fd, wh = lh - fh, ww = lw - fw;
    float od = 1.0f - wd, oh = 1.0f - wh, ow = 1.0f - ww;

    int r00 = (d0 * H_DIM + h0) * W_DIM;
    int r01 = (d0 * H_DIM + h1) * W_DIM;
    int r10 = (d1 * H_DIM + h0) * W_DIM;
    int r11 = (d1 * H_DIM + h1) * W_DIM;

    float w000 = od * oh * ow;
    float w001 = od * oh * ww;
    float w010 = od * wh * ow;
    float w011 = od * wh * ww;
    float w100 = wd * oh * ow;
    float w101 = wd * oh * ww;
    float w110 = wd * wh * ow;
    float w111 = wd * wh * ww;

    float acc0 = 0.0f, acc1 = 0.0f, acc2 = 0.0f;
#define CORNER(ROW, COL, WT)                      \
    {                                             \
        H4 c = v[(ROW) + (COL)];                  \
        acc0 = fmaf(WT, (float)c.x, acc0);        \
        acc1 = fmaf(WT, (float)c.y, acc1);        \
        acc2 = fmaf(WT, (float)c.z, acc2);        \
    }
    CORNER(r00, w0, w000);
    CORNER(r00, w1, w001);
    CORNER(r01, w0, w010);
    CORNER(r01, w1, w011);
    CORNER(r10, w0, w100);
    CORNER(r10, w1, w101);
    CORNER(r11, w0, w110);
    CORNER(r11, w1, w111);
#undef CORNER

    float r0 = flow_d + acc0;
    float r1 = flow_h + acc1;
    float r2 = flow_w + acc2;

    if (MODE == 1) {
        H4 o = {(half_t)r0, (half_t)r1, (half_t)r2, (half_t)0.f};
        reinterpret_cast<H4*>(outp)[idx] = o;
    } else {
        F3 o;
        o.x = r0;
        o.y = r1;
        o.z = r2;
        reinterpret_cast<F3*>(outp)[idx] = o;
    }
}

extern "C" void kernel_launch(void* const* d_in, const int* in_sizes, int n_in,
                              void* d_out, int out_size, void* d_ws, size_t ws_size,
                              hipStream_t stream) {
    const float* vec = (const float*)d_in[0];
    H4* W = (H4*)d_ws;   // fp16 state in workspace (39.3 MB)
    H4* Q = (H4*)d_out;  // d_out doubles as fp16 scratch mid-flight (39.3 < 59 MB)

    int grid = NVOX / 256;  // 19200, exact

    // scale: vec/128 -> W (fp16)
    scale_to_h<<<(NVOX / 4 + 255) / 256, 256, 0, stream>>>(
        (const float4*)vec, W, NVOX / 4);

    // 7 warp steps: W->Q->W->Q->W->Q->W->(fp32)d_out
    warp_h<1><<<grid, 256, 0, stream>>>(W, Q);
    warp_h<1><<<grid, 256, 0, stream>>>(Q, W);
    warp_h<1><<<grid, 256, 0, stream>>>(W, Q);
    warp_h<1><<<grid, 256, 0, stream>>>(Q, W);
    warp_h<1><<<grid, 256, 0, stream>>>(W, Q);
    warp_h<1><<<grid, 256, 0, stream>>>(Q, W);
    warp_h<2><<<grid, 256, 0, stream>>>(W, d_out);  // final, reads ws, writes fp32 AoS
}

// Round 5
// 194.739 us; speedup vs baseline: 3.0319x; 1.3619x over previous
//
#include <hip/hip_runtime.h>

#define D_DIM 160
#define H_DIM 192
#define W_DIM 160
#define NVOX (D_DIM * H_DIM * W_DIM)

typedef _Float16 half_t;
typedef __attribute__((ext_vector_type(4))) _Float16 H4;  // x,y,z,pad : 8 bytes
typedef __attribute__((ext_vector_type(8))) _Float16 H8;  // two adjacent voxels : 16 B

struct F3 {
    float x, y, z;
};

// XCD-chunked remap: blocks with bid%8==x land on XCD x and process the
// contiguous chunk [x*nwg/8, (x+1)*nwg/8) -> per-XCD d-slab, L2-resident window.
__device__ __forceinline__ int swz_bid(int bid, int nwg) {
    int chunk = nwg >> 3;  // nwg divisible by 8
    return (bid & 7) * chunk + (bid >> 3);
}

// vec (fp32 AoS, float4-vectorized) * 1/128 -> fp16 H4 state. 4 voxels/thread.
__global__ __launch_bounds__(256) void scale_to_h(const float4* __restrict__ in,
                                                  H4* __restrict__ out, int n) {
    int i = blockIdx.x * blockDim.x + threadIdx.x;
    if (i >= n) return;
    float4 a = in[3 * i + 0];
    float4 b = in[3 * i + 1];
    float4 c = in[3 * i + 2];
    const float s = 0.0078125f;
    H4 o0 = {(half_t)(a.x * s), (half_t)(a.y * s), (half_t)(a.z * s), (half_t)0.f};
    H4 o1 = {(half_t)(a.w * s), (half_t)(b.x * s), (half_t)(b.y * s), (half_t)0.f};
    H4 o2 = {(half_t)(b.z * s), (half_t)(b.w * s), (half_t)(c.x * s), (half_t)0.f};
    H4 o3 = {(half_t)(c.y * s), (half_t)(c.z * s), (half_t)(c.w * s), (half_t)0.f};
    out[4 * i + 0] = o0;
    out[4 * i + 1] = o1;
    out[4 * i + 2] = o2;
    out[4 * i + 3] = o3;
}

// One scaling-and-squaring step on fp16 state. All math fp32.
// MODE 1: fp16 -> fp16.  MODE 2: fp16 -> fp32 AoS (final step into d_out).
template <int MODE>
__global__ __launch_bounds__(256) void warp_h(const H4* __restrict__ v,
                                              void* __restrict__ outp) {
    int wg = swz_bid(blockIdx.x, gridDim.x);
    int idx = wg * 256 + (int)threadIdx.x;

    int w = idx % W_DIM;
    int t = idx / W_DIM;
    int h = t % H_DIM;
    int d = t / H_DIM;

    H4 f = v[idx];
    float flow_d = (float)f.x;
    float flow_h = (float)f.y;
    float flow_w = (float)f.z;

    float ld = fminf(fmaxf((float)d + flow_d, 0.0f), (float)(D_DIM - 1));
    float lh = fminf(fmaxf((float)h + flow_h, 0.0f), (float)(H_DIM - 1));
    float lw = fminf(fmaxf((float)w + flow_w, 0.0f), (float)(W_DIM - 1));

    float fd = floorf(ld), fh = floorf(lh), fw = floorf(lw);
    int d0 = (int)fd, h0 = (int)fh, w0 = (int)fw;
    int d1 = min(d0 + 1, D_DIM - 1);
    int h1 = min(h0 + 1, H_DIM - 1);

    float wd = ld - fd, wh = lh - fh, ww = lw - fw;
    float od = 1.0f - wd, oh = 1.0f - wh, ow = 1.0f - ww;

    int r00 = (d0 * H_DIM + h0) * W_DIM;
    int r01 = (d0 * H_DIM + h1) * W_DIM;
    int r10 = (d1 * H_DIM + h0) * W_DIM;
    int r11 = (d1 * H_DIM + h1) * W_DIM;

    // paired-corner load: w0 and w1=min(w0+1,W-1) are adjacent -> one 16 B load
    int b = min(w0, W_DIM - 2);
    bool hi_edge = (w0 == W_DIM - 1);  // then both corners are voxel b+1

    float acc0 = 0.0f, acc1 = 0.0f, acc2 = 0.0f;
#define CORNER_PAIR(ROW, WTLO, WTHI)                                           \
    {                                                                          \
        H8 pr = *reinterpret_cast<const H8*>(v + (ROW) + b);                   \
        float l0 = hi_edge ? (float)pr[4] : (float)pr[0];                      \
        float l1 = hi_edge ? (float)pr[5] : (float)pr[1];                      \
        float l2 = hi_edge ? (float)pr[6] : (float)pr[2];                      \
        acc0 = fmaf(WTLO, l0, acc0);                                           \
        acc1 = fmaf(WTLO, l1, acc1);                                           \
        acc2 = fmaf(WTLO, l2, acc2);                                           \
        acc0 = fmaf(WTHI, (float)pr[4], acc0);                                 \
        acc1 = fmaf(WTHI, (float)pr[5], acc1);                                 \
        acc2 = fmaf(WTHI, (float)pr[6], acc2);                                 \
    }
    CORNER_PAIR(r00, od * oh * ow, od * oh * ww);
    CORNER_PAIR(r01, od * wh * ow, od * wh * ww);
    CORNER_PAIR(r10, wd * oh * ow, wd * oh * ww);
    CORNER_PAIR(r11, wd * wh * ow, wd * wh * ww);
#undef CORNER_PAIR

    float r0 = flow_d + acc0;
    float r1 = flow_h + acc1;
    float r2 = flow_w + acc2;

    if (MODE == 1) {
        H4 o = {(half_t)r0, (half_t)r1, (half_t)r2, (half_t)0.f};
        reinterpret_cast<H4*>(outp)[idx] = o;
    } else {
        F3 o;
        o.x = r0;
        o.y = r1;
        o.z = r2;
        reinterpret_cast<F3*>(outp)[idx] = o;
    }
}

extern "C" void kernel_launch(void* const* d_in, const int* in_sizes, int n_in,
                              void* d_out, int out_size, void* d_ws, size_t ws_size,
                              hipStream_t stream) {
    const float* vec = (const float*)d_in[0];
    H4* W = (H4*)d_ws;   // fp16 state in workspace (39.3 MB)
    H4* Q = (H4*)d_out;  // d_out doubles as fp16 scratch mid-flight (39.3 < 59 MB)

    int grid = NVOX / 256;  // 19200, divisible by 8

    // scale: vec/128 -> W (fp16)
    scale_to_h<<<(NVOX / 4 + 255) / 256, 256, 0, stream>>>(
        (const float4*)vec, W, NVOX / 4);

    // 7 warp steps: W->Q->W->Q->W->Q->W->(fp32)d_out
    warp_h<1><<<grid, 256, 0, stream>>>(W, Q);
    warp_h<1><<<grid, 256, 0, stream>>>(Q, W);
    warp_h<1><<<grid, 256, 0, stream>>>(W, Q);
    warp_h<1><<<grid, 256, 0, stream>>>(Q, W);
    warp_h<1><<<grid, 256, 0, stream>>>(W, Q);
    warp_h<1><<<grid, 256, 0, stream>>>(Q, W);
    warp_h<2><<<grid, 256, 0, stream>>>(W, d_out);  // final, reads ws, writes fp32 AoS
}

// Round 6
// 192.125 us; speedup vs baseline: 3.0731x; 1.0136x over previous
//
#include <hip/hip_runtime.h>

#define D_DIM 160
#define H_DIM 192
#define W_DIM 160
#define NVOX (D_DIM * H_DIM * W_DIM)

typedef _Float16 half_t;
typedef __attribute__((ext_vector_type(4))) _Float16 H4;  // x,y,z,pad : 8 bytes
typedef __attribute__((ext_vector_type(8))) _Float16 H8;  // two voxels : 16 B

struct F3 {
    float x, y, z;
};

// vec (fp32 AoS, float4-vectorized) * 1/128 -> fp16 H4 state. 4 voxels/thread.
__global__ __launch_bounds__(256) void scale_to_h(const float4* __restrict__ in,
                                                  H4* __restrict__ out, int n) {
    int i = blockIdx.x * blockDim.x + threadIdx.x;
    if (i >= n) return;
    float4 a = in[3 * i + 0];
    float4 b = in[3 * i + 1];
    float4 c = in[3 * i + 2];
    const float s = 0.0078125f;
    H4 o0 = {(half_t)(a.x * s), (half_t)(a.y * s), (half_t)(a.z * s), (half_t)0.f};
    H4 o1 = {(half_t)(a.w * s), (half_t)(b.x * s), (half_t)(b.y * s), (half_t)0.f};
    H4 o2 = {(half_t)(b.z * s), (half_t)(b.w * s), (half_t)(c.x * s), (half_t)0.f};
    H4 o3 = {(half_t)(c.y * s), (half_t)(c.z * s), (half_t)(c.w * s), (half_t)0.f};
    out[4 * i + 0] = o0;
    out[4 * i + 1] = o1;
    out[4 * i + 2] = o2;
    out[4 * i + 3] = o3;
}

// One voxel's trilinear gather (fp16 state, fp32 math). Adds flow at the end.
__device__ __forceinline__ void warp_voxel(const H4* __restrict__ v, int d, int h,
                                           int w, float fx, float fy, float fz,
                                           float& r0, float& r1, float& r2) {
    float ld = fminf(fmaxf((float)d + fx, 0.0f), (float)(D_DIM - 1));
    float lh = fminf(fmaxf((float)h + fy, 0.0f), (float)(H_DIM - 1));
    float lw = fminf(fmaxf((float)w + fz, 0.0f), (float)(W_DIM - 1));

    float fd = floorf(ld), fh = floorf(lh), fw = floorf(lw);
    int d0 = (int)fd, h0 = (int)fh, w0 = (int)fw;
    int d1 = min(d0 + 1, D_DIM - 1);
    int h1 = min(h0 + 1, H_DIM - 1);

    float wd = ld - fd, wh = lh - fh, ww = lw - fw;
    float od = 1.0f - wd, oh = 1.0f - wh, ow = 1.0f - ww;

    // edge trick on weights: at w0==W-1 (ww==0), pair base shifts to W-2 and
    // the whole w-interp weight moves onto the hi element.
    bool hi_edge = (w0 == W_DIM - 1);
    int b = min(w0, W_DIM - 2);
    float owe = hi_edge ? 0.0f : ow;
    float wwe = hi_edge ? ow : ww;

    int r00 = (d0 * H_DIM + h0) * W_DIM + b;
    int r01 = (d0 * H_DIM + h1) * W_DIM + b;
    int r10 = (d1 * H_DIM + h0) * W_DIM + b;
    int r11 = (d1 * H_DIM + h1) * W_DIM + b;

    float acc0 = 0.0f, acc1 = 0.0f, acc2 = 0.0f;
#define CORNER_PAIR(ROW, FAC)                                   \
    {                                                           \
        H8 pr = *reinterpret_cast<const H8*>(v + (ROW));        \
        float wlo = (FAC)*owe, whi = (FAC)*wwe;                 \
        acc0 = fmaf(wlo, (float)pr[0], acc0);                   \
        acc1 = fmaf(wlo, (float)pr[1], acc1);                   \
        acc2 = fmaf(wlo, (float)pr[2], acc2);                   \
        acc0 = fmaf(whi, (float)pr[4], acc0);                   \
        acc1 = fmaf(whi, (float)pr[5], acc1);                   \
        acc2 = fmaf(whi, (float)pr[6], acc2);                   \
    }
    CORNER_PAIR(r00, od * oh);
    CORNER_PAIR(r01, od * wh);
    CORNER_PAIR(r10, wd * oh);
    CORNER_PAIR(r11, wd * wh);
#undef CORNER_PAIR

    r0 = fx + acc0;
    r1 = fy + acc1;
    r2 = fz + acc2;
}

// One scaling-and-squaring step. 2 w-adjacent voxels per thread.
// MODE 1: fp16 -> fp16.  MODE 2: fp16 -> fp32 AoS (final step into d_out).
// REV: sweep XCD chunk in reverse so pass k+1 starts where pass k ended (L2-hot).
template <int MODE, bool REV>
__global__ __launch_bounds__(256) void warp_h(const H4* __restrict__ v,
                                              void* __restrict__ outp) {
    int chunk = gridDim.x >> 3;  // grid divisible by 8
    int xcd = blockIdx.x & 7;
    int local = blockIdx.x >> 3;
    if (REV) local = chunk - 1 - local;
    int wg = xcd * chunk + local;

    int base = wg * 512 + (int)threadIdx.x * 2;  // even voxel index

    int w = base % W_DIM;  // even, so w+1 stays in the same row
    int t = base / W_DIM;
    int h = t % H_DIM;
    int d = t / H_DIM;

    H8 fl = *reinterpret_cast<const H8*>(v + base);  // flows for both voxels

    float a0, a1, a2, b0, b1, b2;
    warp_voxel(v, d, h, w, (float)fl[0], (float)fl[1], (float)fl[2], a0, a1, a2);
    warp_voxel(v, d, h, w + 1, (float)fl[4], (float)fl[5], (float)fl[6], b0, b1, b2);

    if (MODE == 1) {
        H8 o = {(half_t)a0, (half_t)a1, (half_t)a2, (half_t)0.f,
                (half_t)b0, (half_t)b1, (half_t)b2, (half_t)0.f};
        *reinterpret_cast<H8*>(reinterpret_cast<H4*>(outp) + base) = o;
    } else {
        F3* o = reinterpret_cast<F3*>(outp);
        o[base] = F3{a0, a1, a2};
        o[base + 1] = F3{b0, b1, b2};
    }
}

extern "C" void kernel_launch(void* const* d_in, const int* in_sizes, int n_in,
                              void* d_out, int out_size, void* d_ws, size_t ws_size,
                              hipStream_t stream) {
    const float* vec = (const float*)d_in[0];
    H4* W = (H4*)d_ws;   // fp16 state in workspace (39.3 MB)
    H4* Q = (H4*)d_out;  // d_out doubles as fp16 scratch mid-flight

    // scale: vec/128 -> W (fp16)
    scale_to_h<<<(NVOX / 4 + 255) / 256, 256, 0, stream>>>(
        (const float4*)vec, W, NVOX / 4);

    int grid = NVOX / 512;  // 9600, divisible by 8

    // Alternate sweep direction so each pass starts reading where the previous
    // pass finished writing (per-XCD L2-hot front).
    warp_h<1, false><<<grid, 256, 0, stream>>>(W, Q);
    warp_h<1, true><<<grid, 256, 0, stream>>>(Q, W);
    warp_h<1, false><<<grid, 256, 0, stream>>>(W, Q);
    warp_h<1, true><<<grid, 256, 0, stream>>>(Q, W);
    warp_h<1, false><<<grid, 256, 0, stream>>>(W, Q);
    warp_h<1, true><<<grid, 256, 0, stream>>>(Q, W);
    warp_h<2, false><<<grid, 256, 0, stream>>>(W, d_out);  // final: fp32 AoS
}